// Round 17
// baseline (42.937 us; speedup 1.0000x reference)
//
#include <hip/hip_runtime.h>
#include <hip/hip_fp16.h>

#define NN   2048
#define FIN  128
#define FOUT 64
#define LOG2E 1.44269504088896f

using f16x8 = __attribute__((ext_vector_type(8))) _Float16;
using f16x4 = __attribute__((ext_vector_type(4))) _Float16;
using f16x2 = __attribute__((ext_vector_type(2))) _Float16;
using f32x4 = __attribute__((ext_vector_type(4))) float;
using i32x4 = __attribute__((ext_vector_type(4))) int;

__device__ inline float fast_exp2(float x) {
#if __has_builtin(__builtin_amdgcn_exp2f)
    return __builtin_amdgcn_exp2f(x);
#else
    return exp2f(x);
#endif
}
__device__ inline float fast_rcp(float x) {
#if __has_builtin(__builtin_amdgcn_rcpf)
    return __builtin_amdgcn_rcpf(x);
#else
    return 1.0f / x;
#endif
}
__device__ inline float fast_tanh(float x) {
    float e = fast_exp2(2.0f * LOG2E * x);
    return 1.0f - 2.0f * fast_rcp(e + 1.0f);
}
__device__ inline unsigned cvt2h(float a, float b) {
    return __builtin_bit_cast(unsigned, __builtin_amdgcn_cvt_pkrtz(a, b));
}
__device__ inline f16x2 pkmax(f16x2 a, f16x2 b) {
#if __has_builtin(__builtin_elementwise_max)
    return __builtin_elementwise_max(a, b);
#else
    f16x2 r; r[0] = a[0] > b[0] ? a[0] : b[0]; r[1] = a[1] > b[1] ? a[1] : b[1];
    return r;
#endif
}
__device__ inline unsigned bmask(unsigned wb, int p) {
    unsigned lo = (unsigned)(-(int)((wb >> (2 * p)) & 1u));
    unsigned hi = (unsigned)(-(int)((wb >> (2 * p + 1)) & 1u));
    return (hi & 0xFFFF0000u) | (lo & 0x0000FFFFu);
}

// h16B frag-ordered (16x16x32 B-frag), per (bh): halves offset =
//   bh*131072 + (j>>5)*2048 + (o>>4)*512 + (((j>>3)&3)*16 + (o&15))*8 + (j&7)
// adjbits (ROW-MAJOR dense): [flat_row(8192)][wc(64)] u32

// ---------------------------------------------------------------------------
// Kernel 1: R12 exact — measured at its HBM floor (~15us). Do not touch.
// ---------------------------------------------------------------------------
__global__ __launch_bounds__(256) void k1_proj(
    const float* __restrict__ x, const float* __restrict__ w,
    const float* __restrict__ a_src, const float* __restrict__ a_dst,
    const int* __restrict__ adj,
    _Float16* __restrict__ h16B, float* __restrict__ ssrc, float* __restrict__ sdst,
    unsigned int* __restrict__ adjbits)
{
    __shared__ __align__(16) _Float16 xf[8192];
    __shared__ __align__(16) _Float16 wf[8192];

    const int t    = threadIdx.x;
    const int bx   = blockIdx.x;
    const int bh   = bx >> 5;
    const int tile = bx & 31;
    const int b    = bh >> 2;
    const int h    = bh & 3;
    const int n0   = tile * 64;
    const int wv   = t >> 6;
    const int lane = t & 63;
    const int m    = lane & 15;
    const int g    = lane >> 4;

    {
        const int o  = t & 63;
        const int kc = t >> 6;
        const float* wcol = w + h * FIN * FOUT + o;
        _Float16* dst = wf + ((kc * 4 + (o >> 4)) * 512) + (o & 15) * 8;
#pragma unroll
        for (int hi = 0; hi < 4; ++hi) {
            unsigned u0 = cvt2h(wcol[(kc * 32 + hi * 8 + 0) * FOUT],
                                wcol[(kc * 32 + hi * 8 + 1) * FOUT]);
            unsigned u1 = cvt2h(wcol[(kc * 32 + hi * 8 + 2) * FOUT],
                                wcol[(kc * 32 + hi * 8 + 3) * FOUT]);
            unsigned u2 = cvt2h(wcol[(kc * 32 + hi * 8 + 4) * FOUT],
                                wcol[(kc * 32 + hi * 8 + 5) * FOUT]);
            unsigned u3 = cvt2h(wcol[(kc * 32 + hi * 8 + 6) * FOUT],
                                wcol[(kc * 32 + hi * 8 + 7) * FOUT]);
            *(uint4*)(dst + hi * 128) = uint4{u0, u1, u2, u3};
        }
    }
    {
        const int r  = t >> 2;
        const int kc = t & 3;
        const float* xr = x + ((size_t)(b * NN + n0 + r)) * FIN + kc * 32;
        _Float16* dst = xf + ((r >> 4) * 16 + kc * 4) * 128 + (r & 15) * 8;
#pragma unroll
        for (int g2 = 0; g2 < 4; ++g2) {
            f32x4 va = *(const f32x4*)(xr + g2 * 8);
            f32x4 vb = *(const f32x4*)(xr + g2 * 8 + 4);
            *(uint4*)(dst + g2 * 128) = uint4{cvt2h(va[0], va[1]), cvt2h(va[2], va[3]),
                                              cvt2h(vb[0], vb[1]), cvt2h(vb[2], vb[3])};
        }
    }
    __syncthreads();

    const int rg = wv;
    f32x4 acc0 = {0,0,0,0}, acc1 = {0,0,0,0}, acc2 = {0,0,0,0}, acc3 = {0,0,0,0};
#pragma unroll
    for (int kc = 0; kc < 4; ++kc) {
        f16x8 av = *(const f16x8*)(xf + (rg * 16 + kc * 4 + g) * 128 + m * 8);
        const _Float16* wb_ = wf + kc * 4 * 512 + lane * 8;
        acc0 = __builtin_amdgcn_mfma_f32_16x16x32_f16(av, *(const f16x8*)(wb_), acc0, 0, 0, 0);
        acc1 = __builtin_amdgcn_mfma_f32_16x16x32_f16(av, *(const f16x8*)(wb_ + 512), acc1, 0, 0, 0);
        acc2 = __builtin_amdgcn_mfma_f32_16x16x32_f16(av, *(const f16x8*)(wb_ + 1024), acc2, 0, 0, 0);
        acc3 = __builtin_amdgcn_mfma_f32_16x16x32_f16(av, *(const f16x8*)(wb_ + 1536), acc3, 0, 0, 0);
    }

    float s1r[4] = {0,0,0,0}, s2r[4] = {0,0,0,0};
    const int jg = n0 + rg * 16 + g * 4;
#define PROC(accX, ot)  do {                                                    \
        float asv = a_src[h * FOUT + (ot) * 16 + m];                            \
        float adv = a_dst[h * FOUT + (ot) * 16 + m];                            \
        _Pragma("unroll")                                                       \
        for (int r = 0; r < 4; ++r) {                                           \
            float th = fast_tanh(accX[r]);                                      \
            s1r[r] += th * asv;                                                 \
            s2r[r] += th * adv;                                                 \
        }                                                                       \
        unsigned u0 = cvt2h(accX[0], accX[1]);                                  \
        unsigned u1 = cvt2h(accX[2], accX[3]);                                  \
        int off = bh * 131072 + (jg >> 5) * 2048 + (ot) * 512                   \
                + (((jg >> 3) & 3) * 16 + m) * 8 + (jg & 7);                    \
        *(uint2*)(h16B + off) = uint2{u0, u1};                                  \
    } while (0)
    PROC(acc0, 0); PROC(acc1, 1); PROC(acc2, 2); PROC(acc3, 3);
#undef PROC
#pragma unroll
    for (int msk = 1; msk <= 8; msk <<= 1) {
#pragma unroll
        for (int r = 0; r < 4; ++r) {
            s1r[r] += __shfl_xor(s1r[r], msk);
            s2r[r] += __shfl_xor(s2r[r], msk);
        }
    }
    if (m == 0) {
#pragma unroll
        for (int r = 0; r < 4; ++r) {
            ssrc[bh * NN + jg + r] = s1r[r] * LOG2E;
            sdst[bh * NN + jg + r] = s2r[r] * LOG2E;
        }
    }

    {
        const int  frow0 = bx * 16;
        const int* asrc  = adj + (size_t)frow0 * NN;
#pragma unroll
        for (int w4 = 0; w4 < 4; ++w4) {
            int widx  = t + 256 * w4;
            int row_l = widx >> 6;
            int wc    = widx & 63;
            const i32x4* p = (const i32x4*)(asrc + (size_t)row_l * NN + wc * 32);
            unsigned int wbits = 0;
#pragma unroll
            for (int k = 0; k < 8; ++k) {
                i32x4 v = p[k];
                wbits |= (unsigned int)(v[0] & 1) << (4 * k);
                wbits |= (unsigned int)(v[1] & 1) << (4 * k + 1);
                wbits |= (unsigned int)(v[2] & 1) << (4 * k + 2);
                wbits |= (unsigned int)(v[3] & 1) << (4 * k + 3);
            }
            adjbits[(size_t)(frow0 + row_l) * 64 + wc] = wbits;
        }
    }
}

// ---------------------------------------------------------------------------
// Kernel 2: 512 blocks x 1024 threads (16 waves) = 32 waves/CU from 2
// INDEPENDENT blocks/CU (barrier stalls of one block overlap the other's
// compute). Wave (rg 0..3, quad 0..3): rows rg*16.., j-quarter of each
// 128-j step. 16 steps, 32 barriers/block (half of R12). Per-wave work,
// total LDS instrs, L2 traffic identical to R12. Quad-tree Z combine.
// ---------------------------------------------------------------------------
__global__ __launch_bounds__(1024, 8) void k2_attn(
    const unsigned int* __restrict__ adjbits,
    const _Float16* __restrict__ h16B,
    const float* __restrict__ ssrc, const float* __restrict__ sdst,
    const float* __restrict__ bias, float* __restrict__ out)
{
    // smem: [0,32K) Bf dbuf 2x16KB | [32768,+17408) adjw 64x68 |
    //       [50176,+4K) E1h | [54272,+4K) E2h | [58368,+64) redmax.
    //       comb (40KB, 8 slots x 64 lanes x 20) overlays [0, 40960).
    __shared__ __align__(16) char smem[58432];
    _Float16*     Bf     = (_Float16*)smem;
    unsigned int* adjw   = (unsigned int*)(smem + 32768);  // stride 68 words
    _Float16*     E1h    = (_Float16*)(smem + 50176);
    _Float16*     E2h    = (_Float16*)(smem + 54272);
    float*        redmax = (float*)(smem + 58368);
    float*        comb   = (float*)smem;

    const int t    = threadIdx.x;
    const int wv   = t >> 6;          // 0..15
    const int lane = t & 63;
    const int bh   = blockIdx.x >> 5;
    const int i0   = (blockIdx.x & 31) << 6;    // 64-row tile
    const int b    = bh >> 2;
    const int rg   = wv >> 2;         // 0..3 row-group
    const int quad = wv & 3;          // 0..3 j-quarter
    const int m    = lane & 15;
    const int g    = lane >> 4;

    const _Float16* Bsrc = h16B + bh * 131072;

    // one 16B load per thread per step (16KB = 128 j)
#define STAGE(bufi_, s_)                                                        \
    __builtin_amdgcn_global_load_lds(                                           \
        (const __attribute__((address_space(1))) unsigned int*)(Bsrc + (s_) * 8192 + t * 8), \
        (__attribute__((address_space(3))) unsigned int*)(Bf + (bufi_) * 8192 + t * 8), \
        16, 0, 0)

    STAGE(0, 0);
    // adj slab 16 KB (64 rows x 16 uint4) -> stride-68 LDS; 1 uint4/thread
    {
        const uint4* asrc = (const uint4*)(adjbits + ((size_t)b * NN + i0) * 64);
        uint4 v = asrc[t];
        *(uint4*)(adjw + (t >> 4) * 68 + (t & 15) * 4) = v;
    }
    // fp16 E-tables (2 j per thread) + D-max
    {
        const float* sdp = sdst + bh * NN + t * 2;
        float d0 = sdp[0], d1 = sdp[1];
        *(unsigned*)(E1h + t * 2) = cvt2h(fast_exp2(d0), fast_exp2(d1));
        *(unsigned*)(E2h + t * 2) = cvt2h(fast_exp2(0.2f * d0), fast_exp2(0.2f * d1));
        float dm = fmaxf(d0, d1);
#pragma unroll
        for (int msk = 1; msk <= 32; msk <<= 1) dm = fmaxf(dm, __shfl_xor(dm, msk));
        if (lane == 0) redmax[wv] = dm;
    }
    asm volatile("s_waitcnt vmcnt(0)" ::: "memory");
    __syncthreads();

    float D = redmax[0];
#pragma unroll
    for (int k = 1; k < 16; ++k) D = fmaxf(D, redmax[k]);

    const int row = i0 + rg * 16 + m;
    const float sA = ssrc[bh * NN + row];
    float c = sA + D; c = fmaxf(c, 0.2f * c);
    const float K1f = fast_exp2(sA - c);
    const float K2f = fast_exp2(fmaf(0.2f, sA, -c));
    f16x2 K1h2; { _Float16 q = (_Float16)K1f; K1h2[0] = q; K1h2[1] = q; }
    f16x2 K2h2; { _Float16 q = (_Float16)K2f; K2h2[0] = q; K2h2[1] = q; }

    f32x4 acc0 = {0,0,0,0}, acc1 = {0,0,0,0}, acc2 = {0,0,0,0}, acc3 = {0,0,0,0};
    f32x4 accz = {0,0,0,0};
    f16x8 ones;
#pragma unroll
    for (int i = 0; i < 8; ++i) ones[i] = (_Float16)1.0f;

    const int arow68 = (rg * 16 + m) * 68;

    union afu { f16x8 v; f16x2 p[4]; unsigned u[4]; };

#define EGEN(af_, s_) do {                                                      \
        const int ci_ = 4 * (s_) + quad;                                        \
        unsigned wb_ = adjw[arow68 + ci_] >> (8 * g);                           \
        afu E1u_, E2u_;                                                         \
        E1u_.v = *(const f16x8*)(E1h + ci_ * 32 + 8 * g);                       \
        E2u_.v = *(const f16x8*)(E2h + ci_ * 32 + 8 * g);                       \
        _Pragma("unroll")                                                       \
        for (int p = 0; p < 4; ++p) {                                           \
            f16x2 v1 = K1h2 * E1u_.p[p];                                        \
            f16x2 v2 = K2h2 * E2u_.p[p];                                        \
            af_.u[p] = __builtin_bit_cast(unsigned, pkmax(v1, v2)) & bmask(wb_, p); \
        }                                                                       \
    } while (0)

    afu afc;
    EGEN(afc, 0);

#pragma unroll
    for (int s = 0; s < 16; ++s) {
        if (s < 15) {
            STAGE((s + 1) & 1, s + 1);
            asm volatile("s_waitcnt vmcnt(1)" ::: "memory");
        } else {
            asm volatile("s_waitcnt vmcnt(0)" ::: "memory");
        }
        __builtin_amdgcn_sched_barrier(0);
        __builtin_amdgcn_s_barrier();

        const _Float16* bb = Bf + (s & 1) * 8192 + quad * 2048 + lane * 8;
        f16x8 b0 = *(const f16x8*)(bb);
        f16x8 b1 = *(const f16x8*)(bb + 512);
        f16x8 b2 = *(const f16x8*)(bb + 1024);
        f16x8 b3 = *(const f16x8*)(bb + 1536);

        acc0 = __builtin_amdgcn_mfma_f32_16x16x32_f16(afc.v, b0, acc0, 0, 0, 0);
        acc1 = __builtin_amdgcn_mfma_f32_16x16x32_f16(afc.v, b1, acc1, 0, 0, 0);
        acc2 = __builtin_amdgcn_mfma_f32_16x16x32_f16(afc.v, b2, acc2, 0, 0, 0);
        acc3 = __builtin_amdgcn_mfma_f32_16x16x32_f16(afc.v, b3, acc3, 0, 0, 0);
        accz = __builtin_amdgcn_mfma_f32_16x16x32_f16(afc.v, ones, accz, 0, 0, 0);

        if (s < 15) EGEN(afc, s + 1);

        __builtin_amdgcn_s_barrier();
    }
#undef EGEN
#undef STAGE

    // ---- combine 4 quad-partials (2-round tree; comb overlays loop smem) ----
    __syncthreads();
    if (quad & 1) {                       // quads 1,3 publish
        float* cp = comb + ((rg * 2 + (quad >> 1)) * 64 + lane) * 20;
#pragma unroll
        for (int r = 0; r < 4; ++r) {
            cp[0 + r]  = acc0[r];
            cp[4 + r]  = acc1[r];
            cp[8 + r]  = acc2[r];
            cp[12 + r] = acc3[r];
            cp[16 + r] = accz[r];
        }
    }
    __syncthreads();
    if (!(quad & 1)) {                    // quads 0,2 absorb
        const float* cp = comb + ((rg * 2 + (quad >> 1)) * 64 + lane) * 20;
#pragma unroll
        for (int r = 0; r < 4; ++r) {
            acc0[r] += cp[0 + r];
            acc1[r] += cp[4 + r];
            acc2[r] += cp[8 + r];
            acc3[r] += cp[12 + r];
            accz[r] += cp[16 + r];
        }
    }
    __syncthreads();
    if (quad == 2) {                      // quad 2 publishes its sum
        float* cp = comb + (rg * 64 + lane) * 20;
#pragma unroll
        for (int r = 0; r < 4; ++r) {
            cp[0 + r]  = acc0[r];
            cp[4 + r]  = acc1[r];
            cp[8 + r]  = acc2[r];
            cp[12 + r] = acc3[r];
            cp[16 + r] = accz[r];
        }
    }
    __syncthreads();
    if (quad == 0) {                      // quad 0 finishes + writes
        const float* cp = comb + (rg * 64 + lane) * 20;
        float zs[4];
#pragma unroll
        for (int r = 0; r < 4; ++r) zs[r] = accz[r] + cp[16 + r];
        size_t obase = ((size_t)bh * NN + i0 + rg * 16) * FOUT;
        // C/D layout: col = lane&15, row = g*4 + r
#pragma unroll
        for (int ot = 0; ot < 4; ++ot) {
            float bv = bias[ot * 16 + m];
            f32x4 a = (ot == 0) ? acc0 : (ot == 1) ? acc1 : (ot == 2) ? acc2 : acc3;
#pragma unroll
            for (int r = 0; r < 4; ++r) {
                float v = (a[r] + cp[ot * 4 + r]) / zs[r] + bv;
                out[obase + (size_t)(g * 4 + r) * FOUT + ot * 16 + m] = v;
            }
        }
    }
}

// ---------------------------------------------------------------------------
extern "C" void kernel_launch(void* const* d_in, const int* in_sizes, int n_in,
                              void* d_out, int out_size, void* d_ws, size_t ws_size,
                              hipStream_t stream) {
    (void)in_sizes; (void)n_in; (void)out_size; (void)ws_size;
    const float* x     = (const float*)d_in[0];
    const int*   adj   = (const int*)d_in[1];     // bool -> int32
    const float* w     = (const float*)d_in[2];
    const float* a_src = (const float*)d_in[3];
    const float* a_dst = (const float*)d_in[4];
    const float* bias  = (const float*)d_in[5];
    float*       out   = (float*)d_out;

    _Float16*     h16B    = (_Float16*)d_ws;                               // 4 MB
    float*        ssrc    = (float*)((char*)d_ws + 4194304);               // 128 KB
    float*        sdst    = (float*)((char*)d_ws + 4194304 + 131072);      // 128 KB
    unsigned int* adjbits = (unsigned int*)((char*)d_ws + 4718592);        // 2 MB

    k1_proj<<<512, 256, 0, stream>>>(x, w, a_src, a_dst, adj, h16B, ssrc, sdst, adjbits);
    k2_attn<<<512, 1024, 0, stream>>>(adjbits, h16B, ssrc, sdst, bias, out);
}

// Round 18
// 40.990 us; speedup vs baseline: 1.0475x; 1.0475x over previous
//
#include <hip/hip_runtime.h>
#include <hip/hip_fp16.h>

#define NN   2048
#define FIN  128
#define FOUT 64
#define LOG2E 1.44269504088896f

using f16x8 = __attribute__((ext_vector_type(8))) _Float16;
using f16x4 = __attribute__((ext_vector_type(4))) _Float16;
using f16x2 = __attribute__((ext_vector_type(2))) _Float16;
using f32x4 = __attribute__((ext_vector_type(4))) float;
using i32x4 = __attribute__((ext_vector_type(4))) int;

__device__ inline float fast_exp2(float x) {
#if __has_builtin(__builtin_amdgcn_exp2f)
    return __builtin_amdgcn_exp2f(x);
#else
    return exp2f(x);
#endif
}
__device__ inline float fast_rcp(float x) {
#if __has_builtin(__builtin_amdgcn_rcpf)
    return __builtin_amdgcn_rcpf(x);
#else
    return 1.0f / x;
#endif
}
__device__ inline float fast_tanh(float x) {
    float e = fast_exp2(2.0f * LOG2E * x);
    return 1.0f - 2.0f * fast_rcp(e + 1.0f);
}
__device__ inline unsigned cvt2h(float a, float b) {
    return __builtin_bit_cast(unsigned, __builtin_amdgcn_cvt_pkrtz(a, b));
}
__device__ inline f16x2 pkmax(f16x2 a, f16x2 b) {
#if __has_builtin(__builtin_elementwise_max)
    return __builtin_elementwise_max(a, b);
#else
    f16x2 r; r[0] = a[0] > b[0] ? a[0] : b[0]; r[1] = a[1] > b[1] ? a[1] : b[1];
    return r;
#endif
}
__device__ inline unsigned bmask(unsigned wb, int p) {
    unsigned lo = (unsigned)(-(int)((wb >> (2 * p)) & 1u));
    unsigned hi = (unsigned)(-(int)((wb >> (2 * p + 1)) & 1u));
    return (hi & 0xFFFF0000u) | (lo & 0x0000FFFFu);
}

// h16B frag-ordered (16x16x32 B-frag), per (bh): halves offset =
//   bh*131072 + (j>>5)*2048 + (o>>4)*512 + (((j>>3)&3)*16 + (o&15))*8 + (j&7)
// adjbits (ROW-MAJOR dense): [flat_row(8192)][wc(64)] u32

// ---------------------------------------------------------------------------
// Kernel 1: R12 exact — measured at its HBM floor (~15us, R15 probe).
// ---------------------------------------------------------------------------
__global__ __launch_bounds__(256) void k1_proj(
    const float* __restrict__ x, const float* __restrict__ w,
    const float* __restrict__ a_src, const float* __restrict__ a_dst,
    const int* __restrict__ adj,
    _Float16* __restrict__ h16B, float* __restrict__ ssrc, float* __restrict__ sdst,
    unsigned int* __restrict__ adjbits)
{
    __shared__ __align__(16) _Float16 xf[8192];
    __shared__ __align__(16) _Float16 wf[8192];

    const int t    = threadIdx.x;
    const int bx   = blockIdx.x;
    const int bh   = bx >> 5;
    const int tile = bx & 31;
    const int b    = bh >> 2;
    const int h    = bh & 3;
    const int n0   = tile * 64;
    const int wv   = t >> 6;
    const int lane = t & 63;
    const int m    = lane & 15;
    const int g    = lane >> 4;

    {
        const int o  = t & 63;
        const int kc = t >> 6;
        const float* wcol = w + h * FIN * FOUT + o;
        _Float16* dst = wf + ((kc * 4 + (o >> 4)) * 512) + (o & 15) * 8;
#pragma unroll
        for (int hi = 0; hi < 4; ++hi) {
            unsigned u0 = cvt2h(wcol[(kc * 32 + hi * 8 + 0) * FOUT],
                                wcol[(kc * 32 + hi * 8 + 1) * FOUT]);
            unsigned u1 = cvt2h(wcol[(kc * 32 + hi * 8 + 2) * FOUT],
                                wcol[(kc * 32 + hi * 8 + 3) * FOUT]);
            unsigned u2 = cvt2h(wcol[(kc * 32 + hi * 8 + 4) * FOUT],
                                wcol[(kc * 32 + hi * 8 + 5) * FOUT]);
            unsigned u3 = cvt2h(wcol[(kc * 32 + hi * 8 + 6) * FOUT],
                                wcol[(kc * 32 + hi * 8 + 7) * FOUT]);
            *(uint4*)(dst + hi * 128) = uint4{u0, u1, u2, u3};
        }
    }
    {
        const int r  = t >> 2;
        const int kc = t & 3;
        const float* xr = x + ((size_t)(b * NN + n0 + r)) * FIN + kc * 32;
        _Float16* dst = xf + ((r >> 4) * 16 + kc * 4) * 128 + (r & 15) * 8;
#pragma unroll
        for (int g2 = 0; g2 < 4; ++g2) {
            f32x4 va = *(const f32x4*)(xr + g2 * 8);
            f32x4 vb = *(const f32x4*)(xr + g2 * 8 + 4);
            *(uint4*)(dst + g2 * 128) = uint4{cvt2h(va[0], va[1]), cvt2h(va[2], va[3]),
                                              cvt2h(vb[0], vb[1]), cvt2h(vb[2], vb[3])};
        }
    }
    __syncthreads();

    const int rg = wv;
    f32x4 acc0 = {0,0,0,0}, acc1 = {0,0,0,0}, acc2 = {0,0,0,0}, acc3 = {0,0,0,0};
#pragma unroll
    for (int kc = 0; kc < 4; ++kc) {
        f16x8 av = *(const f16x8*)(xf + (rg * 16 + kc * 4 + g) * 128 + m * 8);
        const _Float16* wb_ = wf + kc * 4 * 512 + lane * 8;
        acc0 = __builtin_amdgcn_mfma_f32_16x16x32_f16(av, *(const f16x8*)(wb_), acc0, 0, 0, 0);
        acc1 = __builtin_amdgcn_mfma_f32_16x16x32_f16(av, *(const f16x8*)(wb_ + 512), acc1, 0, 0, 0);
        acc2 = __builtin_amdgcn_mfma_f32_16x16x32_f16(av, *(const f16x8*)(wb_ + 1024), acc2, 0, 0, 0);
        acc3 = __builtin_amdgcn_mfma_f32_16x16x32_f16(av, *(const f16x8*)(wb_ + 1536), acc3, 0, 0, 0);
    }

    float s1r[4] = {0,0,0,0}, s2r[4] = {0,0,0,0};
    const int jg = n0 + rg * 16 + g * 4;
#define PROC(accX, ot)  do {                                                    \
        float asv = a_src[h * FOUT + (ot) * 16 + m];                            \
        float adv = a_dst[h * FOUT + (ot) * 16 + m];                            \
        _Pragma("unroll")                                                       \
        for (int r = 0; r < 4; ++r) {                                           \
            float th = fast_tanh(accX[r]);                                      \
            s1r[r] += th * asv;                                                 \
            s2r[r] += th * adv;                                                 \
        }                                                                       \
        unsigned u0 = cvt2h(accX[0], accX[1]);                                  \
        unsigned u1 = cvt2h(accX[2], accX[3]);                                  \
        int off = bh * 131072 + (jg >> 5) * 2048 + (ot) * 512                   \
                + (((jg >> 3) & 3) * 16 + m) * 8 + (jg & 7);                    \
        *(uint2*)(h16B + off) = uint2{u0, u1};                                  \
    } while (0)
    PROC(acc0, 0); PROC(acc1, 1); PROC(acc2, 2); PROC(acc3, 3);
#undef PROC
#pragma unroll
    for (int msk = 1; msk <= 8; msk <<= 1) {
#pragma unroll
        for (int r = 0; r < 4; ++r) {
            s1r[r] += __shfl_xor(s1r[r], msk);
            s2r[r] += __shfl_xor(s2r[r], msk);
        }
    }
    if (m == 0) {
#pragma unroll
        for (int r = 0; r < 4; ++r) {
            ssrc[bh * NN + jg + r] = s1r[r] * LOG2E;
            sdst[bh * NN + jg + r] = s2r[r] * LOG2E;
        }
    }

    {
        const int  frow0 = bx * 16;
        const int* asrc  = adj + (size_t)frow0 * NN;
#pragma unroll
        for (int w4 = 0; w4 < 4; ++w4) {
            int widx  = t + 256 * w4;
            int row_l = widx >> 6;
            int wc    = widx & 63;
            const i32x4* p = (const i32x4*)(asrc + (size_t)row_l * NN + wc * 32);
            unsigned int wbits = 0;
#pragma unroll
            for (int k = 0; k < 8; ++k) {
                i32x4 v = p[k];
                wbits |= (unsigned int)(v[0] & 1) << (4 * k);
                wbits |= (unsigned int)(v[1] & 1) << (4 * k + 1);
                wbits |= (unsigned int)(v[2] & 1) << (4 * k + 2);
                wbits |= (unsigned int)(v[3] & 1) << (4 * k + 3);
            }
            adjbits[(size_t)(frow0 + row_l) * 64 + wc] = wbits;
        }
    }
}

// ---------------------------------------------------------------------------
// Kernel 2: R16 exact (best measured: 41.06 total) — R12 structure +
// software-pipelined e-gen.
// ---------------------------------------------------------------------------
__global__ __launch_bounds__(512, 6) void k2_attn(
    const unsigned int* __restrict__ adjbits,
    const _Float16* __restrict__ h16B,
    const float* __restrict__ ssrc, const float* __restrict__ sdst,
    const float* __restrict__ bias, float* __restrict__ out)
{
    __shared__ __align__(16) char smem[42016];
    _Float16*     Bf     = (_Float16*)smem;
    unsigned int* adjw   = (unsigned int*)(smem + 16384);
    _Float16*     E1h    = (_Float16*)(smem + 33792);
    _Float16*     E2h    = (_Float16*)(smem + 37888);
    float*        redmax = (float*)(smem + 41984);
    float*        comb   = (float*)smem;

    const int t    = threadIdx.x;
    const int wv   = t >> 6;
    const int lane = t & 63;
    const int bh   = blockIdx.x >> 5;
    const int i0   = (blockIdx.x & 31) << 6;
    const int b    = bh >> 2;
    const int rg   = wv >> 1;
    const int par  = wv & 1;
    const int m    = lane & 15;
    const int g    = lane >> 4;

    const _Float16* Bsrc = h16B + bh * 131072;

#define STAGE(bufi_, s_)                                                        \
    __builtin_amdgcn_global_load_lds(                                           \
        (const __attribute__((address_space(1))) unsigned int*)(Bsrc + (s_) * 4096 + t * 8), \
        (__attribute__((address_space(3))) unsigned int*)(Bf + (bufi_) * 4096 + t * 8), \
        16, 0, 0)

    STAGE(0, 0);
    {
        const uint4* asrc = (const uint4*)(adjbits + ((size_t)b * NN + i0) * 64);
#pragma unroll
        for (int k = 0; k < 2; ++k) {
            int idx = t + 512 * k;
            uint4 v = asrc[idx];
            *(uint4*)(adjw + (idx >> 4) * 68 + (idx & 15) * 4) = v;
        }
    }
    {
        f32x4 dv = *(const f32x4*)(sdst + bh * NN + t * 4);
        *(uint2*)(E1h + t * 4) = uint2{cvt2h(fast_exp2(dv[0]), fast_exp2(dv[1])),
                                       cvt2h(fast_exp2(dv[2]), fast_exp2(dv[3]))};
        *(uint2*)(E2h + t * 4) = uint2{cvt2h(fast_exp2(0.2f * dv[0]), fast_exp2(0.2f * dv[1])),
                                       cvt2h(fast_exp2(0.2f * dv[2]), fast_exp2(0.2f * dv[3]))};
        float dm = fmaxf(fmaxf(dv[0], dv[1]), fmaxf(dv[2], dv[3]));
#pragma unroll
        for (int msk = 1; msk <= 32; msk <<= 1) dm = fmaxf(dm, __shfl_xor(dm, msk));
        if (lane == 0) redmax[wv] = dm;
    }
    asm volatile("s_waitcnt vmcnt(0)" ::: "memory");
    __syncthreads();

    float D = redmax[0];
#pragma unroll
    for (int k = 1; k < 8; ++k) D = fmaxf(D, redmax[k]);

    const int row = i0 + rg * 16 + m;
    const float sA = ssrc[bh * NN + row];
    float c = sA + D; c = fmaxf(c, 0.2f * c);
    const float K1f = fast_exp2(sA - c);
    const float K2f = fast_exp2(fmaf(0.2f, sA, -c));
    f16x2 K1h2; { _Float16 q = (_Float16)K1f; K1h2[0] = q; K1h2[1] = q; }
    f16x2 K2h2; { _Float16 q = (_Float16)K2f; K2h2[0] = q; K2h2[1] = q; }

    f32x4 acc0 = {0,0,0,0}, acc1 = {0,0,0,0}, acc2 = {0,0,0,0}, acc3 = {0,0,0,0};
    f32x4 accz = {0,0,0,0};
    f16x8 ones;
#pragma unroll
    for (int i = 0; i < 8; ++i) ones[i] = (_Float16)1.0f;

    const int arow68 = (rg * 16 + m) * 68;

    union afu { f16x8 v; f16x2 p[4]; unsigned u[4]; };

#define EGEN(af_, s_) do {                                                      \
        const int ci_ = 2 * (s_) + par;                                         \
        unsigned wb_ = adjw[arow68 + ci_] >> (8 * g);                           \
        afu E1u_, E2u_;                                                         \
        E1u_.v = *(const f16x8*)(E1h + ci_ * 32 + 8 * g);                       \
        E2u_.v = *(const f16x8*)(E2h + ci_ * 32 + 8 * g);                       \
        _Pragma("unroll")                                                       \
        for (int p = 0; p < 4; ++p) {                                           \
            f16x2 v1 = K1h2 * E1u_.p[p];                                        \
            f16x2 v2 = K2h2 * E2u_.p[p];                                        \
            af_.u[p] = __builtin_bit_cast(unsigned, pkmax(v1, v2)) & bmask(wb_, p); \
        }                                                                       \
    } while (0)

    afu afc;
    EGEN(afc, 0);

#pragma unroll
    for (int s = 0; s < 32; ++s) {
        if (s < 31) {
            STAGE((s + 1) & 1, s + 1);
            asm volatile("s_waitcnt vmcnt(1)" ::: "memory");
        } else {
            asm volatile("s_waitcnt vmcnt(0)" ::: "memory");
        }
        __builtin_amdgcn_sched_barrier(0);
        __builtin_amdgcn_s_barrier();

        const _Float16* bb = Bf + (s & 1) * 4096 + par * 2048 + lane * 8;
        f16x8 b0 = *(const f16x8*)(bb);
        f16x8 b1 = *(const f16x8*)(bb + 512);
        f16x8 b2 = *(const f16x8*)(bb + 1024);
        f16x8 b3 = *(const f16x8*)(bb + 1536);

        acc0 = __builtin_amdgcn_mfma_f32_16x16x32_f16(afc.v, b0, acc0, 0, 0, 0);
        acc1 = __builtin_amdgcn_mfma_f32_16x16x32_f16(afc.v, b1, acc1, 0, 0, 0);
        acc2 = __builtin_amdgcn_mfma_f32_16x16x32_f16(afc.v, b2, acc2, 0, 0, 0);
        acc3 = __builtin_amdgcn_mfma_f32_16x16x32_f16(afc.v, b3, acc3, 0, 0, 0);
        accz = __builtin_amdgcn_mfma_f32_16x16x32_f16(afc.v, ones, accz, 0, 0, 0);

        if (s < 31) EGEN(afc, s + 1);

        __builtin_amdgcn_s_barrier();
    }
#undef EGEN
#undef STAGE

    __syncthreads();
    if (par == 1) {
        float* cp = comb + (rg * 64 + lane) * 20;
#pragma unroll
        for (int r = 0; r < 4; ++r) {
            cp[0 + r]  = acc0[r];
            cp[4 + r]  = acc1[r];
            cp[8 + r]  = acc2[r];
            cp[12 + r] = acc3[r];
            cp[16 + r] = accz[r];
        }
    }
    __syncthreads();
    if (par == 0) {
        const float* cp = comb + (rg * 64 + lane) * 20;
        float zs[4];
#pragma unroll
        for (int r = 0; r < 4; ++r) zs[r] = accz[r] + cp[16 + r];
        size_t obase = ((size_t)bh * NN + i0 + rg * 16) * FOUT;
#pragma unroll
        for (int ot = 0; ot < 4; ++ot) {
            float bv = bias[ot * 16 + m];
            f32x4 a = (ot == 0) ? acc0 : (ot == 1) ? acc1 : (ot == 2) ? acc2 : acc3;
#pragma unroll
            for (int r = 0; r < 4; ++r) {
                float v = (a[r] + cp[ot * 4 + r]) / zs[r] + bv;
                out[obase + (size_t)(g * 4 + r) * FOUT + ot * 16 + m] = v;
            }
        }
    }
}

// ---------------------------------------------------------------------------
extern "C" void kernel_launch(void* const* d_in, const int* in_sizes, int n_in,
                              void* d_out, int out_size, void* d_ws, size_t ws_size,
                              hipStream_t stream) {
    (void)in_sizes; (void)n_in; (void)out_size; (void)ws_size;
    const float* x     = (const float*)d_in[0];
    const int*   adj   = (const int*)d_in[1];     // bool -> int32
    const float* w     = (const float*)d_in[2];
    const float* a_src = (const float*)d_in[3];
    const float* a_dst = (const float*)d_in[4];
    const float* bias  = (const float*)d_in[5];
    float*       out   = (float*)d_out;

    _Float16*     h16B    = (_Float16*)d_ws;                               // 4 MB
    float*        ssrc    = (float*)((char*)d_ws + 4194304);               // 128 KB
    float*        sdst    = (float*)((char*)d_ws + 4194304 + 131072);      // 128 KB
    unsigned int* adjbits = (unsigned int*)((char*)d_ws + 4718592);        // 2 MB

    k1_proj<<<512, 256, 0, stream>>>(x, w, a_src, a_dst, adj, h16B, ssrc, sdst, adjbits);
    k2_attn<<<512, 512, 0, stream>>>(adjbits, h16B, ssrc, sdst, bias, out);
}